// Round 7
// baseline (175.886 us; speedup 1.0000x reference)
//
#include <hip/hip_runtime.h>
#include <hip/hip_bf16.h>

// NodeDetector: per-node-masked 2-layer GATv2 forward, delta formulation.
// N=256, C2=64, H=2, E=4352 (incl self loops).
// R7: latency surgery on the two attention kernels.
//  - LDS row staging (coalesced float4) so logits+agg never chase serial
//    global-load chains (R6's agg loop was ~35 dependent L2 loads).
//  - rotated dot loops (cc=(c+e)&63) to kill the 64-way LDS bank conflict
//    (row stride 128 = 0 mod 32 banks when lanes vary e at fixed c).
//  - k_l1base at 256 threads; float4 conversion in k_init.
// Lesson kept from R5: NO software grid barriers on gfx950 (L2 wb/inv per
// fence => 2x regression); kernel boundary is the cheap device barrier.

#define NN 256
#define EDGE_CAP 96   // max in-degree, k_l1base buffers (actual ~35)
#define E2_CAP 64     // max in-degree of node i, k_periter buffers
#define E_CAP 6144    // max edges (actual 4352)
#define M_CAP 8       // max mutual-neighbor count tracked (actual ~1-5)

// ---- converted-input arena offsets (floats) ----
#define OFF_X      0
#define OFF_E      16384
#define OFF_NP     32768
#define OFF_EP     40960
#define OFF_CW0    49152
#define OFF_CW1    65536
#define OFF_CB     81920
#define OFF_L2W    82048
#define OFF_L2B    90240
#define OFF_MP     90304
#define OFF_NPJ    94400
#define OFF_G1WL   98496
#define OFF_G1BL   106688
#define OFF_G1WR   106816
#define OFF_G1BR   115008
#define OFF_G1ATT  115136
#define OFF_G1BIAS 115264
#define OFF_G2WL   115328
#define OFF_G2BL   123520
#define OFF_G2WR   123648
#define OFF_G2BR   131840
#define OFF_G2ATT  131968
#define OFF_G2BIAS 132096
#define OFF_RECW   132160
#define OFF_RECB   136256
#define W_TOTAL    136320

// ---- persistent device-global scratch (fully rewritten every call) ----
__device__ float g_w[W_TOTAL];
__device__ float g_xl0[NN*128], g_xr0[NN*128], g_xlV[NN*128], g_xrV[NN*128];
__device__ float g_xl2_0[NN*128];
__device__ float g_num[NN*128];        // baseline pre-division numerator
__device__ float g_m[NN*2], g_den[NN*2];
__device__ float g_elog[E_CAP*2];      // baseline per-edge logits (CSR pos)
__device__ int   g_in_ptr[NN+1], g_out_ptr[NN+1];
__device__ int   g_in_src[E_CAP], g_out_dst[E_CAP];
__device__ int   g_f32;

// converter block -> (segment, 4096-chunk) static mapping (44 blocks)
__device__ const int c_off[26] = {
  0,16384,32768,40960,49152,65536,81920,82048,90240,90304,94400,98496,
  106688,106816,115008,115136,115264,115328,123520,123648,131840,131968,
  132096,132160,136256,136320};
__device__ const signed char c_seg[44] = {
  0,0,0,0, 1,1,1,1, 2,2, 3,3, 4,4,4,4, 5,5,5,5, 6, 7,7, 8, 9, 10,
  11,11, 12, 13,13, 14, 15, 16, 17,17, 18, 19,19, 20, 21, 22, 23, 24};
__device__ const signed char c_sub[44] = {
  0,1,2,3, 0,1,2,3, 0,1, 0,1, 0,1,2,3, 0,1,2,3, 0, 0,1, 0, 0, 0,
  0,1, 0, 0,1, 0, 0, 0, 0,1, 0, 0,1, 0, 0, 0, 0, 0};

typedef const void* cvp;
__device__ __forceinline__ float b2f(__hip_bfloat16 v) { return __bfloat162float(v); }

// ---------------------------------------------------------------------------
// K0: 45 blocks. All blocks: dtype detect (f32 misread as bf16 => ~half of
// values decode |v|>16 or NaN; bf16 N(0,1) has none). Blocks 0..43 convert a
// 4096-chunk of one input into the f32 arena; block 44 builds CSR with a
// parallel Hillis-Steele scan.
// ---------------------------------------------------------------------------
__global__ __launch_bounds__(256) void k_init(
    cvp x, cvp E_emb, cvp node_proj, cvp emb_proj,
    cvp conv_w0, cvp conv_w1, cvp conv_b, cvp lin2_w, cvp lin2_b,
    cvp masked_proj, cvp normal_proj,
    cvp g1_wl, cvp g1_bl, cvp g1_wr, cvp g1_br, cvp g1_att, cvp g1_bias,
    cvp g2_wl, cvp g2_bl, cvp g2_wr, cvp g2_br, cvp g2_att, cvp g2_bias,
    cvp rec_w, cvp rec_b,
    int n, const int* __restrict__ ei, int E)
{
  const int t = threadIdx.x, b = blockIdx.x;
  __shared__ int s_cnt;
  if (t == 0) s_cnt = 0;
  __syncthreads();
  {
    const __hip_bfloat16* xb = (const __hip_bfloat16*)x;
    const int lim = n < 4096 ? n : 4096;
    int c = 0;
    for (int i = t; i < lim; i += 256) {
      const float v = b2f(xb[i]);
      if (!(fabsf(v) <= 16.f)) c++;
    }
    if (c) atomicAdd(&s_cnt, c);
  }
  __syncthreads();
  const int f = (s_cnt > 64) ? 1 : 0;

  if (b < 44) {
    cvp segs[25] = {x, E_emb, node_proj, emb_proj, conv_w0, conv_w1, conv_b,
                    lin2_w, lin2_b, masked_proj, normal_proj,
                    g1_wl, g1_bl, g1_wr, g1_br, g1_att, g1_bias,
                    g2_wl, g2_bl, g2_wr, g2_br, g2_att, g2_bias,
                    rec_w, rec_b};
    const int s = c_seg[b];
    cvp p = segs[s];
    const int off = c_off[s];
    const int base = (int)c_sub[b] * 4096;
    int lim = (c_off[s+1] - off) - base;
    if (lim > 4096) lim = 4096;
    if (f) {   // pure copy, vectorized (all segment sizes are multiples of 4)
      const float4* pf = (const float4*)((const float*)p + base);
      float4* dst = (float4*)(g_w + off + base);
      for (int i = t; i < (lim >> 2); i += 256) dst[i] = pf[i];
    } else {
      const __hip_bfloat16* pb = (const __hip_bfloat16*)p;
      for (int i = t; i < lim; i += 256) g_w[off+base+i] = b2f(pb[base+i]);
    }
    return;
  }

  // ---- block 44: publish dtype + CSR build (parallel scan) ----
  __shared__ int cin[NN], cou[NN], pin[NN], pou[NN];
  if (E > E_CAP) E = E_CAP;
  if (t == 0) g_f32 = f;
  cin[t] = 0; cou[t] = 0;
  __syncthreads();
  for (int e = t; e < E; e += 256) {
    atomicAdd(&cin[ei[E+e] & (NN-1)], 1);
    atomicAdd(&cou[ei[e]   & (NN-1)], 1);
  }
  __syncthreads();
  pin[t] = cin[t]; pou[t] = cou[t];
  __syncthreads();
  for (int off = 1; off < NN; off <<= 1) {
    int a = 0, c = 0;
    if (t >= off) { a = pin[t-off]; c = pou[t-off]; }
    __syncthreads();
    if (t >= off) { pin[t] += a; pou[t] += c; }
    __syncthreads();
  }
  const int exi = pin[t] - cin[t];   // exclusive prefix
  const int exo = pou[t] - cou[t];
  g_in_ptr[t] = exi; g_out_ptr[t] = exo;
  if (t == NN-1) { g_in_ptr[NN] = pin[t]; g_out_ptr[NN] = pou[t]; }
  cin[t] = exi; cou[t] = exo;        // reuse as cursors
  __syncthreads();
  for (int e = t; e < E; e += 256) {
    const int s = ei[e] & (NN-1), d = ei[E+e] & (NN-1);
    g_in_src[atomicAdd(&cin[d], 1)] = s;
    g_out_dst[atomicAdd(&cou[s], 1)] = d;
  }
}

// ---------------------------------------------------------------------------
// K1: shared dense precompute. One block per node j (128 threads), pure f32.
// ---------------------------------------------------------------------------
__global__ __launch_bounds__(128) void k_dense()
{
  const int j = blockIdx.x, t = threadIdx.x;
  __shared__ float sx[64], sE[64], sxp[128], sEp[128], sh0[128], shm[128],
                   sm0[64], sMm[64], sp0[64], sV[64];
  if (t < 64) { sx[t] = g_w[OFF_X + j*64+t]; sE[t] = g_w[OFF_E + j*64+t]; }
  __syncthreads();
  float a = 0.f, b = 0.f;
  #pragma unroll
  for (int k = 0; k < 64; ++k) {
    a += sx[k] * g_w[OFF_NP + k*128+t];
    b += sE[k] * g_w[OFF_EP + k*128+t];
  }
  sxp[t] = a; sEp[t] = b;
  __syncthreads();
  float xw1 = 0.f, ew0 = 0.f;
  #pragma unroll
  for (int k = 0; k < 128; ++k) {
    xw1 += sxp[k] * g_w[OFF_CW1 + k*128+t];
    ew0 += sEp[k] * g_w[OFF_CW0 + k*128+t];
  }
  const float cb = g_w[OFF_CB + t];
  sh0[t] = tanhf(ew0 + xw1 + cb);
  shm[t] = tanhf(ew0 + cb);
  __syncthreads();
  if (t < 64) {
    float m0 = g_w[OFF_L2B + t], Mm = m0;
    #pragma unroll
    for (int k = 0; k < 128; ++k) {
      const float w = g_w[OFF_L2W + k*64+t];
      m0 += sh0[k]*w; Mm += shm[k]*w;
    }
    sm0[t] = m0; sMm[t] = Mm;
  }
  __syncthreads();
  if (t < 64) {
    float p = 0.f, v = 0.f;
    #pragma unroll
    for (int k = 0; k < 64; ++k) {
      p += sm0[k] * g_w[OFF_NPJ + k*64+t];
      v += sMm[k] * g_w[OFF_MP + k*64+t];
    }
    sp0[t] = p; sV[t] = v;
  }
  __syncthreads();
  float l0 = g_w[OFF_G1BL + t], r0 = g_w[OFF_G1BR + t];
  float lV = l0, rV = r0;
  #pragma unroll
  for (int k = 0; k < 64; ++k) {
    const float wl = g_w[OFF_G1WL + k*128+t], wr = g_w[OFF_G1WR + k*128+t];
    l0 += sp0[k]*wl; r0 += sp0[k]*wr;
    lV += sV[k]*wl;  rV += sV[k]*wr;
  }
  g_xl0[j*128+t] = l0; g_xr0[j*128+t] = r0;
  g_xlV[j*128+t] = lV; g_xrV[j*128+t] = rV;
}

// ---------------------------------------------------------------------------
// K2: baseline layer-1 attention for node j + softmax state for delta path.
// 256 threads. Neighbor xl0 rows staged into LDS via coalesced float4 loads;
// logits + agg read LDS only. Logit dot loops rotated (cc=(c+e)&63) so the
// bank index (c+e)%32 spreads across lanes (stride-128 rows are 0 mod 32).
// ---------------------------------------------------------------------------
__global__ __launch_bounds__(256) void k_l1base()
{
  const int j = blockIdx.x, t = threadIdx.x;
  __shared__ float sxl[EDGE_CAP*128];
  __shared__ float sxr[128], satt[128];
  __shared__ float slog[2][EDGE_CAP], sw[2][EDGE_CAP], sinv[2], sg1[64];
  __shared__ int ssrc[EDGE_CAP];
  const int base = g_in_ptr[j];
  int nE = g_in_ptr[j+1] - base;
  if (nE > EDGE_CAP) nE = EDGE_CAP;
  if (t < 128) { sxr[t] = g_xr0[j*128+t]; satt[t] = g_w[OFF_G1ATT + t]; }
  for (int e = t; e < nE; e += 256) ssrc[e] = g_in_src[base+e];
  __syncthreads();
  // stage neighbor rows (independent coalesced loads -> one latency)
  for (int idx = t; idx < nE*32; idx += 256) {
    const int e = idx >> 5, c4 = idx & 31;
    ((float4*)sxl)[e*32+c4] = ((const float4*)(g_xl0 + ssrc[e]*128))[c4];
  }
  __syncthreads();
  // logits from LDS (rotated)
  for (int idx = t; idx < nE*2; idx += 256) {
    const int e = idx >> 1, h = idx & 1;
    const float* xls = sxl + e*128 + h*64;
    const float* xr  = sxr + h*64;
    const float* at  = satt + h*64;
    float acc = 0.f;
    #pragma unroll
    for (int c = 0; c < 64; ++c) {
      const int cc = (c + e) & 63;
      float v = xls[cc] + xr[cc];
      v = v > 0.f ? v : 0.2f*v;
      acc += at[cc]*v;
    }
    slog[h][e] = acc;
    g_elog[(base+e)*2+h] = acc;
  }
  __syncthreads();
  if (t < 128) {
    const int h = t >> 6, lane = t & 63;
    float m = -1e30f;
    for (int e = lane; e < nE; e += 64) m = fmaxf(m, slog[h][e]);
    for (int o = 1; o < 64; o <<= 1) m = fmaxf(m, __shfl_xor(m, o));
    float ssum = 0.f;
    for (int e = lane; e < nE; e += 64) {
      const float w = __expf(slog[h][e]-m); sw[h][e] = w; ssum += w;
    }
    for (int o = 1; o < 64; o <<= 1) ssum += __shfl_xor(ssum, o);
    if (lane == 0) {
      sinv[h] = 1.f/(ssum + 1e-16f);
      g_m[j*2+h] = m; g_den[j*2+h] = ssum;
    }
  }
  __syncthreads();
  if (t < 64) {   // fused agg (both heads, LDS) + numerator save + elu
    float a0 = 0.f, a1 = 0.f;
    for (int e = 0; e < nE; ++e) {
      a0 += sw[0][e]*sxl[e*128+t];
      a1 += sw[1][e]*sxl[e*128+64+t];
    }
    g_num[j*128+t] = a0; g_num[j*128+64+t] = a1;
    float g = 0.5f*(a0*sinv[0] + a1*sinv[1]) + g_w[OFF_G1BIAS + t];
    g = g > 0.f ? g : expm1f(g);
    sg1[t] = g;
  }
  __syncthreads();
  if (t < 128) {
    float acc = g_w[OFF_G2BL + t];
    #pragma unroll
    for (int k = 0; k < 64; ++k) acc += sg1[k]*g_w[OFF_G2WL + k*128+t];
    g_xl2_0[j*128+t] = acc;
  }
}

// ---------------------------------------------------------------------------
// K3 shared state + delta helper
// ---------------------------------------------------------------------------
struct P3s {
  float xl2e[E2_CAP*128];     // staging for L1 rows, then layer-2 xl rows
  float rtmp[M_CAP*128];      // per-mutual per-head ratio terms
  float g1m[M_CAP*64];        // finalized updated g1 for mutual neighbors
  float sgi[64];              // updated g1 at node i
  float sxlVi[128], sxl0i[128], sxri[128];
  float satt[128], satt2[128];
  float slog[2][E2_CAP], sw[2][E2_CAP], sinv[2];
  float xr2i[128], sg[64];
  int   slotOf[NN];
  unsigned char isInN[NN];
  int   ssrc2[E2_CAP], listM[M_CAP];
  int   nM;
};

// delta-softmax update for mutual neighbor slot m; threads 128..255
// (t 128..191 = head 0, t 192..255 = head 1). Verified in R5/R6.
__device__ __forceinline__ void delta_one(P3s& S, int m, int nMl, int i, int t)
{
  if (m >= nMl) return;
  const int lt = t - 128, h = lt >> 6, c = lt & 63;
  const int j = S.listM[m];
  const float mj = g_m[j*2+h];
  float u = S.sxlVi[lt] + g_xr0[j*128+lt];
  u = u > 0.f ? u : 0.2f*u;
  float ln = S.satt[lt]*u;
  for (int o = 1; o < 64; o <<= 1) ln += __shfl_xor(ln, o);
  const float wn1 = __expf(ln - mj);
  const int jb = g_in_ptr[j], jd = g_in_ptr[j+1] - jb;
  float wo = 0.f; int cnt = 0;
  for (int p = c; p < jd; p += 64)
    if (g_in_src[jb+p] == i) { wo += __expf(g_elog[(jb+p)*2+h] - mj); cnt++; }
  for (int o = 1; o < 64; o <<= 1) {
    wo += __shfl_xor(wo, o); cnt += __shfl_xor(cnt, o);
  }
  const float dd = (float)cnt*wn1 - wo;
  const float dn = (float)cnt*wn1*S.sxlVi[lt] - wo*S.sxl0i[lt];
  S.rtmp[m*128+lt] = (g_num[j*128+lt] + dn) / (g_den[j*2+h] + dd + 1e-16f);
}

// ---------------------------------------------------------------------------
// K3: per-mask-iteration. Block i: full L1 recompute at node i (t<128 pipe),
// delta-softmax for mutual neighbors (t>=128, concurrent), then layer-2
// attention at node i, reconstruction head, tanh, output.
// ---------------------------------------------------------------------------
__global__ __launch_bounds__(256) void k_periter(void* out)
{
  const int i = blockIdx.x, t = threadIdx.x;
  __shared__ P3s S;

  // ---- stage A: init + broadcast loads ----
  if (t < NN) { S.slotOf[t] = -1; S.isInN[t] = 0; }
  if (t == 0) S.nM = 0;
  if (t < 128) {
    S.satt[t]  = g_w[OFF_G1ATT + t];
    S.satt2[t] = g_w[OFF_G2ATT + t];
    S.sxlVi[t] = g_xlV[i*128+t];
    S.sxl0i[t] = g_xl0[i*128+t];
    S.sxri[t]  = g_xrV[i*128+t];
  }
  __syncthreads();
  if (t == 0) S.slotOf[i] = 0;

  // ---- stage B: in-edges of i + in-neighbor bitmap ----
  const int b2 = g_in_ptr[i];
  int nE2 = g_in_ptr[i+1] - b2;
  if (nE2 > E2_CAP) nE2 = E2_CAP;
  for (int e = t; e < nE2; e += 256) {
    const int s = g_in_src[b2+e];
    S.ssrc2[e] = s;
    S.isInN[s] = 1;
  }
  __syncthreads();

  // ---- stage C1: mutual-neighbor set + stage rows into xl2e (xlV subst) ----
  const int ob = g_out_ptr[i], onE = g_out_ptr[i+1] - ob;
  for (int e = t; e < onE; e += 256) {
    const int d = g_out_dst[ob+e];
    if (d != i && S.isInN[d]) {
      if (atomicCAS(&S.slotOf[d], -1, -2) == -1) {
        const int p = atomicAdd(&S.nM, 1);
        if (p < M_CAP) { S.listM[p] = d; S.slotOf[d] = p + 1; }
        else S.slotOf[d] = -1;
      }
    }
  }
  for (int idx = t; idx < nE2*32; idx += 256) {
    const int e = idx >> 5, c4 = idx & 31, s = S.ssrc2[e];
    const float4* src = (s == i) ? (const float4*)S.sxlVi
                                 : (const float4*)(g_xl0 + s*128);
    ((float4*)S.xl2e)[e*32+c4] = src[c4];
  }
  __syncthreads();
  const int nMl = S.nM > M_CAP ? M_CAP : S.nM;

  // ---- stage C2: L1 logits at node i from LDS (rotated) ----
  for (int idx = t; idx < nE2*2; idx += 256) {
    const int e = idx >> 1, h = idx & 1;
    const float* xls = S.xl2e + e*128 + h*64;
    const float* xr  = S.sxri + h*64;
    const float* at  = S.satt + h*64;
    float acc = 0.f;
    #pragma unroll
    for (int c = 0; c < 64; ++c) {
      const int cc = (c + e) & 63;
      float v = xls[cc] + xr[cc];
      v = v > 0.f ? v : 0.2f*v;
      acc += at[cc]*v;
    }
    S.slog[h][e] = acc;
  }
  __syncthreads();

  // ---- stage D: softmax stats at i (t<128) || delta m=0 (t>=128) ----
  if (t < 128) {
    const int h = t >> 6, lane = t & 63;
    float m = -1e30f;
    for (int e = lane; e < nE2; e += 64) m = fmaxf(m, S.slog[h][e]);
    for (int o = 1; o < 64; o <<= 1) m = fmaxf(m, __shfl_xor(m, o));
    float ssum = 0.f;
    for (int e = lane; e < nE2; e += 64) {
      const float w = __expf(S.slog[h][e]-m); S.sw[h][e] = w; ssum += w;
    }
    for (int o = 1; o < 64; o <<= 1) ssum += __shfl_xor(ssum, o);
    if (lane == 0) S.sinv[h] = 1.f/(ssum + 1e-16f);
  } else {
    delta_one(S, 0, nMl, i, t);
  }
  __syncthreads();

  // ---- stage E: agg+elu at i from LDS (t<64) || delta m=1 (t>=128) ----
  if (t < 64) {
    float a0 = 0.f, a1 = 0.f;
    for (int e = 0; e < nE2; ++e) {
      a0 += S.sw[0][e]*S.xl2e[e*128 + t];
      a1 += S.sw[1][e]*S.xl2e[e*128 + 64 + t];
    }
    float g = 0.5f*(a0*S.sinv[0] + a1*S.sinv[1]) + g_w[OFF_G1BIAS + t];
    g = g > 0.f ? g : expm1f(g);
    S.sgi[t] = g;
  } else if (t >= 128) {
    delta_one(S, 1, nMl, i, t);
  }
  __syncthreads();

  // ---- rare extra delta rounds (nM > 2) ----
  for (int m = 2; m < nMl; ++m) {
    if (t >= 128) delta_one(S, m, nMl, i, t);
    __syncthreads();
  }

  // ---- stage G: xr2i (t<128) || finalize g1m (t>=128) ----
  if (t < 128) {
    float v = g_w[OFF_G2BR + t];
    #pragma unroll
    for (int k = 0; k < 64; ++k) v += S.sgi[k]*g_w[OFF_G2WR + k*128+t];
    S.xr2i[t] = v;
  } else {
    for (int idx = t - 128; idx < nMl*64; idx += 128) {
      const int m = idx >> 6, c = idx & 63;
      float g = 0.5f*(S.rtmp[m*128+c] + S.rtmp[m*128+64+c]) + g_w[OFF_G1BIAS + c];
      g = g > 0.f ? g : expm1f(g);
      S.g1m[m*64+c] = g;
    }
  }
  __syncthreads();

  // ---- stage H: per-edge xl2 (changed sources recomputed; overwrites
  //      the staging rows, which are no longer needed) ----
  for (int idx = t; idx < nE2*128; idx += 256) {
    const int e = idx >> 7, c = idx & 127, s = S.ssrc2[e];
    const int sl = S.slotOf[s];
    float v;
    if (sl >= 0) {
      const float* g1r = (sl == 0) ? S.sgi : (S.g1m + (sl-1)*64);
      v = g_w[OFF_G2BL + c];
      #pragma unroll
      for (int k = 0; k < 64; ++k) v += g1r[k]*g_w[OFF_G2WL + k*128+c];
    } else {
      v = g_xl2_0[s*128+c];
    }
    S.xl2e[e*128+c] = v;
  }
  __syncthreads();

  // ---- stage I: layer-2 logits (rotated) ----
  for (int idx = t; idx < nE2*2; idx += 256) {
    const int e = idx >> 1, h = idx & 1;
    const float* xle = S.xl2e + e*128 + h*64;
    const float* xr  = S.xr2i + h*64;
    const float* at  = S.satt2 + h*64;
    float acc = 0.f;
    #pragma unroll
    for (int c = 0; c < 64; ++c) {
      const int cc = (c + e) & 63;
      float v = xle[cc] + xr[cc];
      v = v > 0.f ? v : 0.2f*v;
      acc += at[cc]*v;
    }
    S.slog[h][e] = acc;
  }
  __syncthreads();

  // ---- stage J: layer-2 softmax stats ----
  if (t < 128) {
    const int h = t >> 6, lane = t & 63;
    float m = -1e30f;
    for (int e = lane; e < nE2; e += 64) m = fmaxf(m, S.slog[h][e]);
    for (int o = 1; o < 64; o <<= 1) m = fmaxf(m, __shfl_xor(m, o));
    float ssum = 0.f;
    for (int e = lane; e < nE2; e += 64) {
      const float w = __expf(S.slog[h][e]-m); S.sw[h][e] = w; ssum += w;
    }
    for (int o = 1; o < 64; o <<= 1) ssum += __shfl_xor(ssum, o);
    if (lane == 0) S.sinv[h] = 1.f/(ssum + 1e-16f);
  }
  __syncthreads();

  // ---- stage K: layer-2 agg + elu (both heads, t<64) ----
  if (t < 64) {
    float a0 = 0.f, a1 = 0.f;
    for (int e = 0; e < nE2; ++e) {
      a0 += S.sw[0][e]*S.xl2e[e*128 + t];
      a1 += S.sw[1][e]*S.xl2e[e*128 + 64 + t];
    }
    float g = 0.5f*(a0*S.sinv[0] + a1*S.sinv[1]) + g_w[OFF_G2BIAS + t];
    g = g > 0.f ? g : expm1f(g);
    S.sg[t] = g;
  }
  __syncthreads();

  // ---- stage L: reconstruction head + tanh + store ----
  if (t < 64) {
    float v = g_w[OFF_RECB + t];
    #pragma unroll
    for (int c = 0; c < 64; ++c) v += S.sg[c]*g_w[OFF_RECW + c*64+t];
    const float r = tanhf(v);
    if (g_f32) ((float*)out)[i*64+t] = r;
    else       ((__hip_bfloat16*)out)[i*64+t] = __float2bfloat16(r);
  }
}

// ---------------------------------------------------------------------------
extern "C" void kernel_launch(void* const* d_in, const int* in_sizes, int n_in,
                              void* d_out, int out_size, void* d_ws, size_t ws_size,
                              hipStream_t stream)
{
  const int* ei = (const int*)d_in[2];
  const int E = in_sizes[2] / 2;

  k_init<<<45, 256, 0, stream>>>(
      d_in[0], d_in[1], d_in[3], d_in[4], d_in[5], d_in[6], d_in[7],
      d_in[8], d_in[9], d_in[10], d_in[11], d_in[12], d_in[13], d_in[14],
      d_in[15], d_in[16], d_in[17], d_in[18], d_in[19], d_in[20], d_in[21],
      d_in[22], d_in[23], d_in[24], d_in[25],
      in_sizes[0], ei, E);
  k_dense<<<NN, 128, 0, stream>>>();
  k_l1base<<<NN, 256, 0, stream>>>();
  k_periter<<<NN, 256, 0, stream>>>(d_out);
}

// Round 8
// 171.833 us; speedup vs baseline: 1.0236x; 1.0236x over previous
//
#include <hip/hip_runtime.h>
#include <hip/hip_bf16.h>

// NodeDetector: per-node-masked 2-layer GATv2 forward, delta formulation.
// N=256, C2=64, H=2, E=4352 (incl self loops).
// R8: 3 launches. The f32 arena + converter launch is gone: every kernel is
// compiled twice via template<bool F32> bodies selected by a block-uniform
// branch (avoids R3's per-element dtype-branch poison with zero conversion
// cost). CSR build rides as blocks 256/257 of the dense grid (independent
// work, hidden under dense). Attention bodies are the R6-measured-best forms
// (R7 showed LDS staging/rotation is neutral-to-negative there).
// Lessons kept: NO software grid barriers on gfx950 (R5: L2 wb/inv per fence
// => 2x regression); kernel boundary is the cheap device barrier.

#define NN 256
#define EDGE_CAP 96   // max in-degree, k_l1base buffers (actual ~35)
#define E2_CAP 64     // max in-degree of node i, k_periter buffers
#define E_CAP 6144    // max edges (actual 4352)
#define M_CAP 8       // max mutual-neighbor count tracked (actual ~1-5)

// ---- persistent device-global scratch (fully rewritten every call) ----
__device__ float g_xl0[NN*128], g_xr0[NN*128], g_xlV[NN*128], g_xrV[NN*128];
__device__ float g_xl2_0[NN*128];
__device__ float g_num[NN*128];        // baseline pre-division numerator
__device__ float g_m[NN*2], g_den[NN*2];
__device__ float g_elog[E_CAP*2];      // baseline per-edge logits (CSR pos)
__device__ int   g_in_ptr[NN+1], g_out_ptr[NN+1];
__device__ int   g_in_src[E_CAP], g_out_dst[E_CAP];
__device__ int   g_f32;

typedef const void* cvp;
__device__ __forceinline__ float b2f(__hip_bfloat16 v) { return __bfloat162float(v); }

template<bool F32>
__device__ __forceinline__ float LD(cvp p, int i) {
  if constexpr (F32) return ((const float*)p)[i];
  else return b2f(((const __hip_bfloat16*)p)[i]);
}

// ---------------------------------------------------------------------------
// K_pre: 258 blocks x 128. Blocks 0..255: dense precompute for node j=b.
// Blocks 256/257: CSR build (in / out). Every block self-detects dtype
// (f32 misread as bf16 => ~25% of elements decode |v|>16 or NaN; bf16 N(0,1)
// has none) — deterministic, no cross-block communication needed.
// ---------------------------------------------------------------------------
struct DenseS { float sx[64], sE[64], sxp[128], sEp[128], sh0[128], shm[128],
                      sm0[64], sMm[64], sp0[64], sV[64]; };
struct CsrS { int cnt[NN], cur[NN]; };

template<bool F32>
__device__ __forceinline__ void dense_body(DenseS& S, int j, int t,
    cvp x, cvp Ee, cvp np_, cvp ep_, cvp cw0, cvp cw1, cvp cb_,
    cvp l2w, cvp l2b, cvp mp, cvp npj, cvp wl_, cvp bl_, cvp wr_, cvp br_)
{
  if (t < 64) { S.sx[t] = LD<F32>(x, j*64+t); S.sE[t] = LD<F32>(Ee, j*64+t); }
  __syncthreads();
  float a = 0.f, b = 0.f;
  #pragma unroll
  for (int k = 0; k < 64; ++k) {
    a += S.sx[k] * LD<F32>(np_, k*128+t);
    b += S.sE[k] * LD<F32>(ep_, k*128+t);
  }
  S.sxp[t] = a; S.sEp[t] = b;
  __syncthreads();
  float xw1 = 0.f, ew0 = 0.f;
  #pragma unroll
  for (int k = 0; k < 128; ++k) {
    xw1 += S.sxp[k] * LD<F32>(cw1, k*128+t);
    ew0 += S.sEp[k] * LD<F32>(cw0, k*128+t);
  }
  const float cb = LD<F32>(cb_, t);
  S.sh0[t] = tanhf(ew0 + xw1 + cb);
  S.shm[t] = tanhf(ew0 + cb);
  __syncthreads();
  if (t < 64) {
    float m0 = LD<F32>(l2b, t), Mm = m0;
    #pragma unroll
    for (int k = 0; k < 128; ++k) {
      const float w = LD<F32>(l2w, k*64+t);
      m0 += S.sh0[k]*w; Mm += S.shm[k]*w;
    }
    S.sm0[t] = m0; S.sMm[t] = Mm;
  }
  __syncthreads();
  if (t < 64) {
    float p = 0.f, v = 0.f;
    #pragma unroll
    for (int k = 0; k < 64; ++k) {
      p += S.sm0[k] * LD<F32>(npj, k*64+t);   // normal_proj
      v += S.sMm[k] * LD<F32>(mp,  k*64+t);   // masked_proj
    }
    S.sp0[t] = p; S.sV[t] = v;
  }
  __syncthreads();
  float l0 = LD<F32>(bl_, t), r0 = LD<F32>(br_, t);
  float lV = l0, rV = r0;
  #pragma unroll
  for (int k = 0; k < 64; ++k) {
    const float wl = LD<F32>(wl_, k*128+t), wr = LD<F32>(wr_, k*128+t);
    l0 += S.sp0[k]*wl; r0 += S.sp0[k]*wr;
    lV += S.sV[k]*wl;  rV += S.sV[k]*wr;
  }
  g_xl0[j*128+t] = l0; g_xr0[j*128+t] = r0;
  g_xlV[j*128+t] = lV; g_xrV[j*128+t] = rV;
}

__global__ __launch_bounds__(128) void k_pre(
    cvp x, cvp Ee, cvp np_, cvp ep_, cvp cw0, cvp cw1, cvp cb_,
    cvp l2w, cvp l2b, cvp mp, cvp npj, cvp wl_, cvp bl_, cvp wr_, cvp br_,
    const int* __restrict__ ei, int n, int E)
{
  const int t = threadIdx.x, b = blockIdx.x;
  __shared__ union { DenseS d; CsrS c; } S;
  __shared__ int s_cnt;
  if (t == 0) s_cnt = 0;
  __syncthreads();
  {
    const __hip_bfloat16* xb = (const __hip_bfloat16*)x;
    const int lim = n < 2048 ? n : 2048;
    int c = 0;
    for (int i = t; i < lim; i += 128) {
      const float v = b2f(xb[i]);
      if (!(fabsf(v) <= 16.f)) c++;   // counts NaN too
    }
    if (c) atomicAdd(&s_cnt, c);
  }
  __syncthreads();
  const int f = (s_cnt > 32) ? 1 : 0;
  if (E > E_CAP) E = E_CAP;

  if (b < NN) {
    if (f) dense_body<true >(S.d, b, t, x,Ee,np_,ep_,cw0,cw1,cb_,l2w,l2b,mp,npj,wl_,bl_,wr_,br_);
    else   dense_body<false>(S.d, b, t, x,Ee,np_,ep_,cw0,cw1,cb_,l2w,l2b,mp,npj,wl_,bl_,wr_,br_);
    return;
  }

  // ---- CSR blocks: dir 0 = in (by dst), dir 1 = out (by src) ----
  const int dir = b - NN;
  if (dir == 0 && t == 0) g_f32 = f;
  S.c.cnt[t] = 0; S.c.cnt[t+128] = 0;
  __syncthreads();
  for (int e = t; e < E; e += 128) {
    const int key = (dir == 0) ? (ei[E+e] & (NN-1)) : (ei[e] & (NN-1));
    atomicAdd(&S.c.cnt[key], 1);
  }
  __syncthreads();
  if (t == 0) {   // serial scan: hidden under the 256 dense blocks
    int run = 0;
    for (int nn = 0; nn < NN; ++nn) { S.c.cur[nn] = run; run += S.c.cnt[nn]; }
  }
  __syncthreads();
  int* gptr = (dir == 0) ? g_in_ptr : g_out_ptr;
  gptr[t] = S.c.cur[t]; gptr[t+128] = S.c.cur[t+128];
  if (t == 0) gptr[NN] = E;
  __syncthreads();
  for (int e = t; e < E; e += 128) {
    const int s = ei[e] & (NN-1), d = ei[E+e] & (NN-1);
    if (dir == 0) g_in_src [atomicAdd(&S.c.cur[d], 1)] = s;
    else          g_out_dst[atomicAdd(&S.c.cur[s], 1)] = d;
  }
}

// ---------------------------------------------------------------------------
// K_l1base: baseline layer-1 attention for node j + softmax state for the
// delta path (g_m/g_den/g_num/g_elog) + xl2_0 tail. R6-measured-best body.
// ---------------------------------------------------------------------------
struct L1S {
  float sxr[128], satt[128], slog[2][EDGE_CAP], sw[2][EDGE_CAP];
  float sinv[2], sg1[64];
  int ssrc[EDGE_CAP];
};

template<bool F32>
__device__ __forceinline__ void l1_body(L1S& S, int j, int t,
    cvp att, cvp bias, cvp g2wl, cvp g2bl)
{
  const int base = g_in_ptr[j];
  int nE = g_in_ptr[j+1] - base;
  if (nE > EDGE_CAP) nE = EDGE_CAP;
  S.sxr[t] = g_xr0[j*128+t];
  S.satt[t] = LD<F32>(att, t);
  for (int e = t; e < nE; e += 128) S.ssrc[e] = g_in_src[base+e];
  __syncthreads();
  for (int idx = t; idx < nE*2; idx += 128) {
    const int e = idx >> 1, h = idx & 1, s = S.ssrc[e];
    const float* xls = g_xl0 + s*128 + h*64;
    float acc = 0.f;
    #pragma unroll
    for (int c = 0; c < 64; ++c) {
      float v = xls[c] + S.sxr[h*64+c];
      v = v > 0.f ? v : 0.2f*v;
      acc += S.satt[h*64+c]*v;
    }
    S.slog[h][e] = acc;
    g_elog[(base+e)*2+h] = acc;
  }
  __syncthreads();
  {
    const int h = t >> 6, lane = t & 63;
    float m = -1e30f;
    for (int e = lane; e < nE; e += 64) m = fmaxf(m, S.slog[h][e]);
    for (int o = 1; o < 64; o <<= 1) m = fmaxf(m, __shfl_xor(m, o));
    float ssum = 0.f;
    for (int e = lane; e < nE; e += 64) {
      const float w = __expf(S.slog[h][e]-m); S.sw[h][e] = w; ssum += w;
    }
    for (int o = 1; o < 64; o <<= 1) ssum += __shfl_xor(ssum, o);
    if (lane == 0) {
      S.sinv[h] = 1.f/(ssum + 1e-16f);
      g_m[j*2+h] = m; g_den[j*2+h] = ssum;
    }
  }
  __syncthreads();
  if (t < 64) {   // fused agg (both heads) + numerator save + elu
    float a0 = 0.f, a1 = 0.f;
    for (int e = 0; e < nE; ++e) {
      const float* xs = g_xl0 + S.ssrc[e]*128;
      a0 += S.sw[0][e]*xs[t];
      a1 += S.sw[1][e]*xs[64+t];
    }
    g_num[j*128+t] = a0; g_num[j*128+64+t] = a1;
    float g = 0.5f*(a0*S.sinv[0] + a1*S.sinv[1]) + LD<F32>(bias, t);
    g = g > 0.f ? g : expm1f(g);
    S.sg1[t] = g;
  }
  __syncthreads();
  float acc = LD<F32>(g2bl, t);
  #pragma unroll
  for (int k = 0; k < 64; ++k) acc += S.sg1[k]*LD<F32>(g2wl, k*128+t);
  g_xl2_0[j*128+t] = acc;
}

__global__ __launch_bounds__(128) void k_l1base(cvp att, cvp bias, cvp g2wl, cvp g2bl)
{
  __shared__ L1S S;
  const int f = g_f32;
  if (f) l1_body<true >(S, blockIdx.x, threadIdx.x, att, bias, g2wl, g2bl);
  else   l1_body<false>(S, blockIdx.x, threadIdx.x, att, bias, g2wl, g2bl);
}

// ---------------------------------------------------------------------------
// K_periter: per-mask-iteration (R6-measured-best body). Block i: full L1
// recompute at node i (t<128), delta-softmax for mutual neighbors (t>=128,
// concurrent), layer-2 attention at i, reconstruction head, tanh, store.
// ---------------------------------------------------------------------------
struct P3s {
  float xl2e[E2_CAP*128];
  float rtmp[M_CAP*128];
  float g1m[M_CAP*64];
  float sgi[64];
  float sxlVi[128], sxl0i[128], sxri[128];
  float satt[128], satt2[128];
  float slog[2][E2_CAP], sw[2][E2_CAP], sinv[2];
  float xr2i[128], sg[64];
  int   slotOf[NN];
  unsigned char isInN[NN];
  int   ssrc2[E2_CAP], listM[M_CAP];
  int   nM;
};

// delta-softmax update for mutual neighbor slot m; threads 128..255
// (t 128..191 = head 0, t 192..255 = head 1). Verified R5/R6.
__device__ __forceinline__ void delta_one(P3s& S, int m, int nMl, int i, int t)
{
  if (m >= nMl) return;
  const int lt = t - 128, h = lt >> 6, c = lt & 63;
  const int j = S.listM[m];
  const float mj = g_m[j*2+h];
  float u = S.sxlVi[lt] + g_xr0[j*128+lt];
  u = u > 0.f ? u : 0.2f*u;
  float ln = S.satt[lt]*u;
  for (int o = 1; o < 64; o <<= 1) ln += __shfl_xor(ln, o);
  const float wn1 = __expf(ln - mj);
  const int jb = g_in_ptr[j], jd = g_in_ptr[j+1] - jb;
  float wo = 0.f; int cnt = 0;
  for (int p = c; p < jd; p += 64)
    if (g_in_src[jb+p] == i) { wo += __expf(g_elog[(jb+p)*2+h] - mj); cnt++; }
  for (int o = 1; o < 64; o <<= 1) {
    wo += __shfl_xor(wo, o); cnt += __shfl_xor(cnt, o);
  }
  const float dd = (float)cnt*wn1 - wo;
  const float dn = (float)cnt*wn1*S.sxlVi[lt] - wo*S.sxl0i[lt];
  S.rtmp[m*128+lt] = (g_num[j*128+lt] + dn) / (g_den[j*2+h] + dd + 1e-16f);
}

template<bool F32>
__device__ __forceinline__ void periter_body(P3s& S, int i, int t,
    cvp att1, cvp bias1, cvp g2wl, cvp g2bl, cvp g2wr, cvp g2br,
    cvp att2, cvp bias2, cvp recw, cvp recb, void* out)
{
  // ---- stage A: init + broadcast loads ----
  if (t < NN) { S.slotOf[t] = -1; S.isInN[t] = 0; }
  if (t == 0) S.nM = 0;
  if (t < 128) {
    S.satt[t]  = LD<F32>(att1, t);
    S.satt2[t] = LD<F32>(att2, t);
    S.sxlVi[t] = g_xlV[i*128+t];
    S.sxl0i[t] = g_xl0[i*128+t];
    S.sxri[t]  = g_xrV[i*128+t];
  }
  __syncthreads();
  if (t == 0) S.slotOf[i] = 0;

  // ---- stage B: in-edges of i + in-neighbor bitmap ----
  const int b2 = g_in_ptr[i];
  int nE2 = g_in_ptr[i+1] - b2;
  if (nE2 > E2_CAP) nE2 = E2_CAP;
  for (int e = t; e < nE2; e += 256) {
    const int s = g_in_src[b2+e];
    S.ssrc2[e] = s;
    S.isInN[s] = 1;
  }
  __syncthreads();

  // ---- stage C: mutual-neighbor set + L1 logits at node i ----
  const int ob = g_out_ptr[i], onE = g_out_ptr[i+1] - ob;
  for (int e = t; e < onE; e += 256) {
    const int d = g_out_dst[ob+e];
    if (d != i && S.isInN[d]) {
      if (atomicCAS(&S.slotOf[d], -1, -2) == -1) {
        const int p = atomicAdd(&S.nM, 1);
        if (p < M_CAP) { S.listM[p] = d; S.slotOf[d] = p + 1; }
        else S.slotOf[d] = -1;
      }
    }
  }
  for (int idx = t; idx < nE2*2; idx += 256) {
    const int e = idx >> 1, h = idx & 1, s = S.ssrc2[e];
    const float* xls = (s == i) ? (S.sxlVi + h*64) : (g_xl0 + s*128 + h*64);
    float acc = 0.f;
    #pragma unroll
    for (int c = 0; c < 64; ++c) {
      float v = xls[c] + S.sxri[h*64+c];
      v = v > 0.f ? v : 0.2f*v;
      acc += S.satt[h*64+c]*v;
    }
    S.slog[h][e] = acc;
  }
  __syncthreads();
  const int nMl = S.nM > M_CAP ? M_CAP : S.nM;

  // ---- stage D: softmax stats at i (t<128) || delta m=0 (t>=128) ----
  if (t < 128) {
    const int h = t >> 6, lane = t & 63;
    float m = -1e30f;
    for (int e = lane; e < nE2; e += 64) m = fmaxf(m, S.slog[h][e]);
    for (int o = 1; o < 64; o <<= 1) m = fmaxf(m, __shfl_xor(m, o));
    float ssum = 0.f;
    for (int e = lane; e < nE2; e += 64) {
      const float w = __expf(S.slog[h][e]-m); S.sw[h][e] = w; ssum += w;
    }
    for (int o = 1; o < 64; o <<= 1) ssum += __shfl_xor(ssum, o);
    if (lane == 0) S.sinv[h] = 1.f/(ssum + 1e-16f);
  } else {
    delta_one(S, 0, nMl, i, t);
  }
  __syncthreads();

  // ---- stage E: agg+elu at i (t<64) || delta m=1 (t>=128) ----
  if (t < 64) {
    float a0 = 0.f, a1 = 0.f;
    for (int e = 0; e < nE2; ++e) {
      const int s = S.ssrc2[e];
      const float* xs = (s == i) ? S.sxlVi : (g_xl0 + s*128);
      a0 += S.sw[0][e]*xs[t];
      a1 += S.sw[1][e]*xs[64+t];
    }
    float g = 0.5f*(a0*S.sinv[0] + a1*S.sinv[1]) + LD<F32>(bias1, t);
    g = g > 0.f ? g : expm1f(g);
    S.sgi[t] = g;
  } else if (t >= 128) {
    delta_one(S, 1, nMl, i, t);
  }
  __syncthreads();

  // ---- rare extra delta rounds (nM > 2) ----
  for (int m = 2; m < nMl; ++m) {
    if (t >= 128) delta_one(S, m, nMl, i, t);
    __syncthreads();
  }

  // ---- stage G: xr2i (t<128) || finalize g1m (t>=128) ----
  if (t < 128) {
    float v = LD<F32>(g2br, t);
    #pragma unroll
    for (int k = 0; k < 64; ++k) v += S.sgi[k]*LD<F32>(g2wr, k*128+t);
    S.xr2i[t] = v;
  } else {
    for (int idx = t - 128; idx < nMl*64; idx += 128) {
      const int m = idx >> 6, c = idx & 63;
      float g = 0.5f*(S.rtmp[m*128+c] + S.rtmp[m*128+64+c]) + LD<F32>(bias1, c);
      g = g > 0.f ? g : expm1f(g);
      S.g1m[m*64+c] = g;
    }
  }
  __syncthreads();

  // ---- stage H: per-edge xl2 (changed sources recomputed) ----
  for (int idx = t; idx < nE2*128; idx += 256) {
    const int e = idx >> 7, c = idx & 127, s = S.ssrc2[e];
    const int sl = S.slotOf[s];
    float v;
    if (sl >= 0) {
      const float* g1r = (sl == 0) ? S.sgi : (S.g1m + (sl-1)*64);
      v = LD<F32>(g2bl, c);
      #pragma unroll
      for (int k = 0; k < 64; ++k) v += g1r[k]*LD<F32>(g2wl, k*128+c);
    } else {
      v = g_xl2_0[s*128+c];
    }
    S.xl2e[e*128+c] = v;
  }
  __syncthreads();

  // ---- stage I: layer-2 logits ----
  for (int idx = t; idx < nE2*2; idx += 256) {
    const int e = idx >> 1, h = idx & 1;
    const float* xle = S.xl2e + e*128 + h*64;
    float acc = 0.f;
    #pragma unroll
    for (int c = 0; c < 64; ++c) {
      float v = xle[c] + S.xr2i[h*64+c];
      v = v > 0.f ? v : 0.2f*v;
      acc += S.satt2[h*64+c]*v;
    }
    S.slog[h][e] = acc;
  }
  __syncthreads();

  // ---- stage J: layer-2 softmax stats ----
  if (t < 128) {
    const int h = t >> 6, lane = t & 63;
    float m = -1e30f;
    for (int e = lane; e < nE2; e += 64) m = fmaxf(m, S.slog[h][e]);
    for (int o = 1; o < 64; o <<= 1) m = fmaxf(m, __shfl_xor(m, o));
    float ssum = 0.f;
    for (int e = lane; e < nE2; e += 64) {
      const float w = __expf(S.slog[h][e]-m); S.sw[h][e] = w; ssum += w;
    }
    for (int o = 1; o < 64; o <<= 1) ssum += __shfl_xor(ssum, o);
    if (lane == 0) S.sinv[h] = 1.f/(ssum + 1e-16f);
  }
  __syncthreads();

  // ---- stage K: layer-2 agg + elu (both heads, t<64) ----
  if (t < 64) {
    float a0 = 0.f, a1 = 0.f;
    for (int e = 0; e < nE2; ++e) {
      a0 += S.sw[0][e]*S.xl2e[e*128 + t];
      a1 += S.sw[1][e]*S.xl2e[e*128 + 64 + t];
    }
    float g = 0.5f*(a0*S.sinv[0] + a1*S.sinv[1]) + LD<F32>(bias2, t);
    g = g > 0.f ? g : expm1f(g);
    S.sg[t] = g;
  }
  __syncthreads();

  // ---- stage L: reconstruction head + tanh + store ----
  if (t < 64) {
    float v = LD<F32>(recb, t);
    #pragma unroll
    for (int c = 0; c < 64; ++c) v += S.sg[c]*LD<F32>(recw, c*64+t);
    const float r = tanhf(v);
    if constexpr (F32) ((float*)out)[i*64+t] = r;
    else               ((__hip_bfloat16*)out)[i*64+t] = __float2bfloat16(r);
  }
}

__global__ __launch_bounds__(256) void k_periter(
    cvp att1, cvp bias1, cvp g2wl, cvp g2bl, cvp g2wr, cvp g2br,
    cvp att2, cvp bias2, cvp recw, cvp recb, void* out)
{
  __shared__ P3s S;
  const int f = g_f32;
  if (f) periter_body<true >(S, blockIdx.x, threadIdx.x,
      att1, bias1, g2wl, g2bl, g2wr, g2br, att2, bias2, recw, recb, out);
  else   periter_body<false>(S, blockIdx.x, threadIdx.x,
      att1, bias1, g2wl, g2bl, g2wr, g2br, att2, bias2, recw, recb, out);
}

// ---------------------------------------------------------------------------
extern "C" void kernel_launch(void* const* d_in, const int* in_sizes, int n_in,
                              void* d_out, int out_size, void* d_ws, size_t ws_size,
                              hipStream_t stream)
{
  const int* ei = (const int*)d_in[2];
  const int E = in_sizes[2] / 2;

  k_pre<<<NN+2, 128, 0, stream>>>(
      d_in[0], d_in[1], d_in[3], d_in[4], d_in[5], d_in[6], d_in[7],
      d_in[8], d_in[9], d_in[10], d_in[11], d_in[12], d_in[13], d_in[14],
      d_in[15], ei, in_sizes[0], E);
  k_l1base<<<NN, 128, 0, stream>>>(d_in[16], d_in[17], d_in[18], d_in[19]);
  k_periter<<<NN, 256, 0, stream>>>(d_in[16], d_in[17], d_in[18], d_in[19],
      d_in[20], d_in[21], d_in[22], d_in[23], d_in[24], d_in[25], d_out);
}